// Round 1
// 1402.042 us; speedup vs baseline: 1.0978x; 1.0978x over previous
//
#include <hip/hip_runtime.h>
#include <hip/hip_bf16.h>

#define IN_DIM 64
#define H 128
#define G3 384
#define OUT_DIM 64
#define Bb 1024
#define Tt 512
#define NEG 0.01f
#define EPSLN 1e-5f

#define CHUNK 16
#define NCHUNK (Tt / CHUNK)
#define BPB 2            // batch rows per block -> 512 blocks = 2 blocks/CU

typedef __bf16 bf16_t;
typedef __bf16 bf16x8 __attribute__((ext_vector_type(8)));
typedef float f32x4 __attribute__((ext_vector_type(4)));

// ---- LDS layout (bytes), all 16B aligned ----
#define GXS 392
#define GX_OFF 0          // bf16 [32][392]   gates_x tile (2 batches x 16 t)
#define HAS 136
#define HA_OFF 25088      // bf16 [32][136]   h1/h2/y staging
#define HPB_OFF 33792     // bf16 [2][16][136] h_prev ping-pong (rows b*4 valid)
#define RED_OFF 42496     // f32  [32][8]     LN cross-wave partials
#define MNR_OFF 43520     // f32  [32][2]     mean/rstd
#define VEC_OFF 43776     // f32  [1600]      bias/gain vectors
#define INI_OFF 50176     // int  [2][17]     init flags (+1 lookahead)
#define SMEM_BYTES 50320

#define V_B1 0
#define V_G1 128
#define V_BE1 256
#define V_B2 384
#define V_G2 512
#define V_BE2 640
#define V_BIH 768
#define V_BHH 1152
#define V_BOUT 1536

// bf16 weight workspace offsets (elements)
#define WS_W1 0
#define WS_W2 8192
#define WS_WIH 24576
#define WS_WHH 73728
#define WS_WOUT 122880
#define WS_ELEMS 131072

#define MFMA(a, b, c) __builtin_amdgcn_mfma_f32_16x16x32_bf16((a), (b), (c), 0, 0, 0)

template <bool WSB>
__device__ __forceinline__ bf16x8 ldfrag(const float* pf, const bf16_t* pb) {
    if constexpr (WSB) {
        return *(const bf16x8*)pb;
    } else {
        bf16x8 f;
#pragma unroll
        for (int j = 0; j < 8; ++j) f[j] = (bf16_t)pf[j];
        return f;
    }
}

__global__ void cvt_weights(const float* __restrict__ W1, const float* __restrict__ W2,
                            const float* __restrict__ Wih, const float* __restrict__ Whh,
                            const float* __restrict__ Wout, bf16_t* __restrict__ ws) {
    int i = blockIdx.x * 256 + threadIdx.x;   // grid 512*256 == WS_ELEMS
    float v;
    if (i < WS_W2) v = W1[i];
    else if (i < WS_WIH) v = W2[i - WS_W2];
    else if (i < WS_WHH) v = Wih[i - WS_WIH];
    else if (i < WS_WOUT) v = Whh[i - WS_WHH];
    else v = Wout[i - WS_WOUT];
    ws[i] = (bf16_t)v;
}

template <bool WSB>
__global__ void __launch_bounds__(256, 2) gru_fused(
    const float* __restrict__ x, const int* __restrict__ is_init,
    const float* __restrict__ hx,
    const float* __restrict__ W1, const float* __restrict__ b1,
    const float* __restrict__ g1, const float* __restrict__ be1,
    const float* __restrict__ W2, const float* __restrict__ b2,
    const float* __restrict__ g2, const float* __restrict__ be2,
    const float* __restrict__ Wih, const float* __restrict__ Whh,
    const float* __restrict__ bih, const float* __restrict__ bhh,
    const float* __restrict__ Wout, const float* __restrict__ bout,
    const bf16_t* __restrict__ wsb,
    float* __restrict__ out)
{
    extern __shared__ char smem[];
    bf16_t* GX  = (bf16_t*)(smem + GX_OFF);
    bf16_t* HA  = (bf16_t*)(smem + HA_OFF);
    bf16_t* HPB = (bf16_t*)(smem + HPB_OFF);
    float*  RED = (float*) (smem + RED_OFF);
    float*  MNR = (float*) (smem + MNR_OFF);
    float*  VEC = (float*) (smem + VEC_OFF);
    int*    INI = (int*)   (smem + INI_OFF);

    const bf16_t* W1B  = wsb + WS_W1;
    const bf16_t* W2B  = wsb + WS_W2;
    const bf16_t* WihB = wsb + WS_WIH;
    const bf16_t* WhhB = wsb + WS_WHH;
    const bf16_t* WoB  = wsb + WS_WOUT;

    const int tid  = threadIdx.x;
    const int w    = tid >> 6;        // wave 0..3
    const int lane = tid & 63;
    const int ln   = lane & 15;
    const int quad = lane >> 4;
    const int b0   = blockIdx.x * BPB;

    // ---- one-time setup ----
    for (int i = tid; i < H; i += 256) {
        VEC[V_B1 + i] = b1[i];  VEC[V_G1 + i] = g1[i];  VEC[V_BE1 + i] = be1[i];
        VEC[V_B2 + i] = b2[i];  VEC[V_G2 + i] = g2[i];  VEC[V_BE2 + i] = be2[i];
    }
    for (int i = tid; i < G3; i += 256) {
        VEC[V_BIH + i] = bih[i];  VEC[V_BHH + i] = bhh[i];
    }
    if (tid < OUT_DIM) VEC[V_BOUT + tid] = bout[tid];
    for (int i = tid; i < 2 * 16 * HAS; i += 256) HPB[i] = (bf16_t)0.f;
    __syncthreads();

    // h0 in registers of the owning lanes (quad == batch), plus bf16 copy in
    // HPB buffer 0 at row b*4 (so batch b lands in C-row b*4 = quad b, reg 0).
    float hp[2] = {0.f, 0.f};
    if (quad < BPB) {
        int b = quad;
        int im = is_init[(size_t)(b0 + b) * Tt];
#pragma unroll
        for (int sub = 0; sub < 2; ++sub) {
            int j = w * 32 + sub * 16 + ln;
            float v = im ? 0.f : hx[(size_t)(b0 + b) * H + j];
            hp[sub] = v;
            HPB[b * 4 * HAS + j] = (bf16_t)v;   // buffer 0 (t=0 reads parity 0)
        }
    }
    // hoist b_hh slices for this lane's columns
    float bh[3][2];
#pragma unroll
    for (int g = 0; g < 3; ++g)
#pragma unroll
        for (int sub = 0; sub < 2; ++sub)
            bh[g][sub] = bhh[g * H + w * 32 + sub * 16 + ln];

    // hoist W_hh B-fragments in VGPRs (used 512x on the serial path)
    bf16x8 whhf[6][4];
#pragma unroll
    for (int ntl = 0; ntl < 6; ++ntl) {
        int gate = ntl >> 1, sub = ntl & 1;
        int n = gate * H + w * 32 + sub * 16 + ln;
#pragma unroll
        for (int ks = 0; ks < 4; ++ks) {
            size_t off = (size_t)n * H + ks * 32 + quad * 8;
            whhf[ntl][ks] = ldfrag<WSB>(Whh + off, WhhB + off);
        }
    }
    __syncthreads();

    for (int tc = 0; tc < NCHUNK; ++tc) {
        const int t0 = tc * CHUNK;

        // ============ phase A: MLP + gates for 32 rows (2b x 16t) ============
        // rr = b_local*16 + dt ; A-frag row = ln = dt, M-tile mt = b_local.
        f32x4 vs[BPB][2];

        // ---- S1: h1 = LN(lrelu(x @ W1^T + b1)); wave w owns cols [32w,32w+32)
        {
            bf16x8 w1f[2][2];
#pragma unroll
            for (int ntl = 0; ntl < 2; ++ntl) {
                int n = w * 32 + ntl * 16 + ln;
#pragma unroll
                for (int ks = 0; ks < 2; ++ks) {
                    size_t off = (size_t)n * IN_DIM + ks * 32 + quad * 8;
                    w1f[ntl][ks] = ldfrag<WSB>(W1 + off, W1B + off);
                }
            }
#pragma unroll
            for (int mt = 0; mt < BPB; ++mt) {
                const float* xr_ = x + ((size_t)(b0 + mt) * Tt + t0 + ln) * IN_DIM;
                bf16x8 a0, a1;
#pragma unroll
                for (int j = 0; j < 8; ++j) {
                    a0[j] = (bf16_t)xr_[quad * 8 + j];
                    a1[j] = (bf16_t)xr_[32 + quad * 8 + j];
                }
#pragma unroll
                for (int ntl = 0; ntl < 2; ++ntl) {
                    f32x4 c = {0.f, 0.f, 0.f, 0.f};
                    c = MFMA(a0, w1f[ntl][0], c);
                    c = MFMA(a1, w1f[ntl][1], c);
                    vs[mt][ntl] = c;
                }
            }
            float bv[2], gv[2], bev[2];
#pragma unroll
            for (int ntl = 0; ntl < 2; ++ntl) {
                int n = w * 32 + ntl * 16 + ln;
                bv[ntl] = VEC[V_B1 + n]; gv[ntl] = VEC[V_G1 + n]; bev[ntl] = VEC[V_BE1 + n];
            }
#pragma unroll
            for (int mt = 0; mt < BPB; ++mt) {
#pragma unroll
                for (int reg = 0; reg < 4; ++reg) {
                    float v0 = vs[mt][0][reg] + bv[0]; v0 = v0 > 0.f ? v0 : NEG * v0;
                    float v1 = vs[mt][1][reg] + bv[1]; v1 = v1 > 0.f ? v1 : NEG * v1;
                    vs[mt][0][reg] = v0; vs[mt][1][reg] = v1;
                    float s = v0 + v1, q = v0 * v0 + v1 * v1;
#pragma unroll
                    for (int d = 1; d < 16; d <<= 1) { s += __shfl_xor(s, d); q += __shfl_xor(q, d); }
                    if (ln == 0) {
                        int rr = mt * 16 + quad * 4 + reg;
                        RED[rr * 8 + w] = s; RED[rr * 8 + 4 + w] = q;
                    }
                }
            }
            __syncthreads();
            if (tid < 32) {
                float s = RED[tid * 8] + RED[tid * 8 + 1] + RED[tid * 8 + 2] + RED[tid * 8 + 3];
                float q = RED[tid * 8 + 4] + RED[tid * 8 + 5] + RED[tid * 8 + 6] + RED[tid * 8 + 7];
                float mean = s * (1.f / H);
                float var = q * (1.f / H) - mean * mean;
                MNR[tid * 2] = mean; MNR[tid * 2 + 1] = rsqrtf(var + EPSLN);
            }
            __syncthreads();
#pragma unroll
            for (int mt = 0; mt < BPB; ++mt) {
#pragma unroll
                for (int reg = 0; reg < 4; ++reg) {
                    int rr = mt * 16 + quad * 4 + reg;
                    float mean = MNR[rr * 2], rstd = MNR[rr * 2 + 1];
#pragma unroll
                    for (int ntl = 0; ntl < 2; ++ntl) {
                        int n = w * 32 + ntl * 16 + ln;
                        HA[rr * HAS + n] = (bf16_t)(gv[ntl] * (vs[mt][ntl][reg] - mean) * rstd + bev[ntl]);
                    }
                }
            }
            __syncthreads();
        }

        // ---- S2: h2 = LN(lrelu(h1 @ W2^T + b2)) (K=128)
        {
            bf16x8 w2f[2][4];
#pragma unroll
            for (int ntl = 0; ntl < 2; ++ntl) {
                int n = w * 32 + ntl * 16 + ln;
#pragma unroll
                for (int ks = 0; ks < 4; ++ks) {
                    size_t off = (size_t)n * H + ks * 32 + quad * 8;
                    w2f[ntl][ks] = ldfrag<WSB>(W2 + off, W2B + off);
                }
            }
#pragma unroll
            for (int mt = 0; mt < BPB; ++mt) {
                bf16x8 af[4];
#pragma unroll
                for (int ks = 0; ks < 4; ++ks)
                    af[ks] = *(const bf16x8*)(HA + (mt * 16 + ln) * HAS + ks * 32 + quad * 8);
#pragma unroll
                for (int ntl = 0; ntl < 2; ++ntl) {
                    f32x4 c = {0.f, 0.f, 0.f, 0.f};
#pragma unroll
                    for (int ks = 0; ks < 4; ++ks) c = MFMA(af[ks], w2f[ntl][ks], c);
                    vs[mt][ntl] = c;
                }
            }
            float bv[2], gv[2], bev[2];
#pragma unroll
            for (int ntl = 0; ntl < 2; ++ntl) {
                int n = w * 32 + ntl * 16 + ln;
                bv[ntl] = VEC[V_B2 + n]; gv[ntl] = VEC[V_G2 + n]; bev[ntl] = VEC[V_BE2 + n];
            }
#pragma unroll
            for (int mt = 0; mt < BPB; ++mt) {
#pragma unroll
                for (int reg = 0; reg < 4; ++reg) {
                    float v0 = vs[mt][0][reg] + bv[0]; v0 = v0 > 0.f ? v0 : NEG * v0;
                    float v1 = vs[mt][1][reg] + bv[1]; v1 = v1 > 0.f ? v1 : NEG * v1;
                    vs[mt][0][reg] = v0; vs[mt][1][reg] = v1;
                    float s = v0 + v1, q = v0 * v0 + v1 * v1;
#pragma unroll
                    for (int d = 1; d < 16; d <<= 1) { s += __shfl_xor(s, d); q += __shfl_xor(q, d); }
                    if (ln == 0) {
                        int rr = mt * 16 + quad * 4 + reg;
                        RED[rr * 8 + w] = s; RED[rr * 8 + 4 + w] = q;
                    }
                }
            }
            __syncthreads();
            if (tid < 32) {
                float s = RED[tid * 8] + RED[tid * 8 + 1] + RED[tid * 8 + 2] + RED[tid * 8 + 3];
                float q = RED[tid * 8 + 4] + RED[tid * 8 + 5] + RED[tid * 8 + 6] + RED[tid * 8 + 7];
                float mean = s * (1.f / H);
                float var = q * (1.f / H) - mean * mean;
                MNR[tid * 2] = mean; MNR[tid * 2 + 1] = rsqrtf(var + EPSLN);
            }
            __syncthreads();
#pragma unroll
            for (int mt = 0; mt < BPB; ++mt) {
#pragma unroll
                for (int reg = 0; reg < 4; ++reg) {
                    int rr = mt * 16 + quad * 4 + reg;
                    float mean = MNR[rr * 2], rstd = MNR[rr * 2 + 1];
#pragma unroll
                    for (int ntl = 0; ntl < 2; ++ntl) {
                        int n = w * 32 + ntl * 16 + ln;
                        HA[rr * HAS + n] = (bf16_t)(gv[ntl] * (vs[mt][ntl][reg] - mean) * rstd + bev[ntl]);
                    }
                }
            }
            __syncthreads();
        }

        // ---- S3: gx = h2 @ W_ih^T + b_ih -> GX (bf16). wave w: n-tiles [6w,6w+6)
        // split in halves of 3 n-tiles to bound live registers (whhf stays resident)
#pragma unroll
        for (int half = 0; half < 2; ++half) {
            bf16x8 wf[3][4];
            float bv[3];
#pragma unroll
            for (int k3 = 0; k3 < 3; ++k3) {
                int n = (w * 6 + half * 3 + k3) * 16 + ln;
                bv[k3] = VEC[V_BIH + n];
#pragma unroll
                for (int ks = 0; ks < 4; ++ks) {
                    size_t off = (size_t)n * H + ks * 32 + quad * 8;
                    wf[k3][ks] = ldfrag<WSB>(Wih + off, WihB + off);
                }
            }
#pragma unroll
            for (int mt = 0; mt < BPB; ++mt) {
                bf16x8 af[4];
#pragma unroll
                for (int ks = 0; ks < 4; ++ks)
                    af[ks] = *(const bf16x8*)(HA + (mt * 16 + ln) * HAS + ks * 32 + quad * 8);
#pragma unroll
                for (int k3 = 0; k3 < 3; ++k3) {
                    int n = (w * 6 + half * 3 + k3) * 16 + ln;
                    f32x4 c = {0.f, 0.f, 0.f, 0.f};
#pragma unroll
                    for (int ks = 0; ks < 4; ++ks) c = MFMA(af[ks], wf[k3][ks], c);
#pragma unroll
                    for (int reg = 0; reg < 4; ++reg)
                        GX[(mt * 16 + quad * 4 + reg) * GXS + n] = (bf16_t)(c[reg] + bv[k3]);
                }
            }
        }
        // init flags for this chunk (+1 lookahead)
        if (tid < BPB * 17) {
            int b = tid / 17, s = tid % 17;
            int t = t0 + s;
            INI[tid] = (t < Tt) ? is_init[(size_t)(b0 + b) * Tt + t] : 0;
        }

        // ============ recurrent: 16 GRU steps, ONE barrier per step ==========
        // HPB is ping-pong on global-step parity: step t reads buf (t&1),
        // writes buf (t+1)&1 -> write/read of each buffer are barrier-separated.
        for (int s = 0; s < CHUNK; ++s) {
            __syncthreads();   // prev HPB write + GX/INI visible
            const int t = t0 + s;
            const int rp = t & 1;
            bf16x8 af[4];
#pragma unroll
            for (int ks = 0; ks < 4; ++ks)
                af[ks] = *(const bf16x8*)(HPB + rp * 16 * HAS + ln * HAS + ks * 32 + quad * 8);
            f32x4 gc[6];
#pragma unroll
            for (int ntl = 0; ntl < 6; ++ntl) {
                f32x4 c = {0.f, 0.f, 0.f, 0.f};
#pragma unroll
                for (int ks = 0; ks < 4; ++ks) c = MFMA(af[ks], whhf[ntl][ks], c);
                gc[ntl] = c;
            }
            // batch b sits in C-row b*4 = (quad b, reg 0): gate math in-place,
            // no LDS roundtrip, no second barrier.
            if (quad < BPB) {
                const int b = quad;
                bf16_t* hw = HPB + (rp ^ 1) * 16 * HAS + b * 4 * HAS;
                const int rbase = (b * 16 + s) * GXS;
#pragma unroll
                for (int sub = 0; sub < 2; ++sub) {
                    int j = w * 32 + sub * 16 + ln;
                    float xr = (float)GX[rbase + j];
                    float xz = (float)GX[rbase + H + j];
                    float xn = (float)GX[rbase + 2 * H + j];
                    float hr = gc[sub][0]     + bh[0][sub];
                    float hz = gc[2 + sub][0] + bh[1][sub];
                    float hn = gc[4 + sub][0] + bh[2][sub];
                    float r = 1.f / (1.f + __expf(-(xr + hr)));
                    float z = 1.f / (1.f + __expf(-(xz + hz)));
                    float a = xn + r * hn;
                    a = fminf(fmaxf(a, -15.f), 15.f);
                    float e = __expf(-2.f * a);
                    float nn = (1.f - e) / (1.f + e);
                    float hnew = (1.f - z) * nn + z * hp[sub];
                    HA[(b * 16 + s) * HAS + j] = (bf16_t)hnew;      // y for out-proj
                    float hm;
                    if (t < Tt - 1) {
                        hm = INI[b * 17 + s + 1] ? 0.f : hnew;      // fold next reset
                    } else {
                        hm = hnew;
                        out[(size_t)Bb * Tt * OUT_DIM + (size_t)(b0 + b) * H + j] = hnew;
                    }
                    hp[sub] = hm;
                    hw[j] = (bf16_t)hm;
                }
            }
        }
        __syncthreads();   // y (HA) complete before out-projection

        // ============ out-projection: y @ W_out^T + b_out ====================
        {
            int o = w * 16 + ln;
            size_t ob = (size_t)o * H;
            bf16x8 wof[4];
#pragma unroll
            for (int ks = 0; ks < 4; ++ks)
                wof[ks] = ldfrag<WSB>(Wout + ob + ks * 32 + quad * 8, WoB + ob + ks * 32 + quad * 8);
            float bo = VEC[V_BOUT + o];
#pragma unroll
            for (int mt = 0; mt < BPB; ++mt) {
                bf16x8 af[4];
#pragma unroll
                for (int ks = 0; ks < 4; ++ks)
                    af[ks] = *(const bf16x8*)(HA + (mt * 16 + ln) * HAS + ks * 32 + quad * 8);
                f32x4 c = {0.f, 0.f, 0.f, 0.f};
#pragma unroll
                for (int ks = 0; ks < 4; ++ks) c = MFMA(af[ks], wof[ks], c);
#pragma unroll
                for (int reg = 0; reg < 4; ++reg)
                    out[((size_t)(b0 + mt) * Tt + t0 + quad * 4 + reg) * OUT_DIM + o] = c[reg] + bo;
            }
        }
        __syncthreads();  // protect HA/GX reuse next chunk
    }
}

extern "C" void kernel_launch(void* const* d_in, const int* in_sizes, int n_in,
                              void* d_out, int out_size, void* d_ws, size_t ws_size,
                              hipStream_t stream) {
    const float* x      = (const float*)d_in[0];
    const int*   is_init= (const int*)  d_in[1];
    const float* hx     = (const float*)d_in[2];
    const float* W1     = (const float*)d_in[3];
    const float* b1     = (const float*)d_in[4];
    const float* g1     = (const float*)d_in[5];
    const float* be1    = (const float*)d_in[6];
    const float* W2     = (const float*)d_in[7];
    const float* b2     = (const float*)d_in[8];
    const float* g2     = (const float*)d_in[9];
    const float* be2    = (const float*)d_in[10];
    const float* Wih    = (const float*)d_in[11];
    const float* Whh    = (const float*)d_in[12];
    const float* bih    = (const float*)d_in[13];
    const float* bhh    = (const float*)d_in[14];
    const float* Wout   = (const float*)d_in[15];
    const float* bout   = (const float*)d_in[16];
    float* out = (float*)d_out;

    const bool usews = (d_ws != nullptr) && (ws_size >= (size_t)(WS_ELEMS * sizeof(bf16_t)));
    if (usews) {
        bf16_t* ws = (bf16_t*)d_ws;
        cvt_weights<<<WS_ELEMS / 256, 256, 0, stream>>>(W1, W2, Wih, Whh, Wout, ws);
        hipFuncSetAttribute((const void*)gru_fused<true>,
                            hipFuncAttributeMaxDynamicSharedMemorySize, SMEM_BYTES);
        gru_fused<true><<<Bb / BPB, 256, SMEM_BYTES, stream>>>(
            x, is_init, hx, W1, b1, g1, be1, W2, b2, g2, be2,
            Wih, Whh, bih, bhh, Wout, bout, ws, out);
    } else {
        hipFuncSetAttribute((const void*)gru_fused<false>,
                            hipFuncAttributeMaxDynamicSharedMemorySize, SMEM_BYTES);
        gru_fused<false><<<Bb / BPB, 256, SMEM_BYTES, stream>>>(
            x, is_init, hx, W1, b1, g1, be1, W2, b2, g2, be2,
            Wih, Whh, bih, bhh, Wout, bout, nullptr, out);
    }
}

// Round 2
// 1346.401 us; speedup vs baseline: 1.1431x; 1.0413x over previous
//
#include <hip/hip_runtime.h>
#include <hip/hip_bf16.h>

#define IN_DIM 64
#define H 128
#define G3 384
#define OUT_DIM 64
#define Bb 1024
#define Tt 512
#define NEG 0.01f
#define EPSLN 1e-5f

#define CHUNK 16
#define NTILE (Tt / CHUNK)      // 32 tiles of 16 steps

typedef __bf16 bf16_t;
typedef __bf16 bf16x8 __attribute__((ext_vector_type(8)));
typedef float f32x4 __attribute__((ext_vector_type(4)));

#define MFMA(a, b, c) __builtin_amdgcn_mfma_f32_16x16x32_bf16((a), (b), (c), 0, 0, 0)

// ---- bf16 weight workspace offsets (elements) ----
#define WS_W1 0
#define WS_W2 8192
#define WS_WIH 24576
#define WS_WHH 73728
#define WS_WOUT 122880
#define WS_ELEMS 131072
// ---- workspace byte offsets ----
#define WS_E_OFF 262144                       // f32 [1024][32][128] = 16 MB
#define WS_R_OFF (WS_E_OFF + 16777216)        // int [1024][32]
#define WS_RA_OFF (WS_R_OFF + 131072)         // int [1024][32]
#define WS_NEED (WS_RA_OFF + 131072)          // 17,301,504 bytes

#define HAS 136
#define GXS 392

// =====================================================================
// weight f32 -> bf16 convert, + zero the R_A flag array
// =====================================================================
__global__ void cvt_weights(const float* __restrict__ W1, const float* __restrict__ W2,
                            const float* __restrict__ Wih, const float* __restrict__ Whh,
                            const float* __restrict__ Wout, bf16_t* __restrict__ ws,
                            int* __restrict__ RA) {
    int i = blockIdx.x * 256 + threadIdx.x;   // grid 512*256 == WS_ELEMS
    float v;
    if (i < WS_W2) v = W1[i];
    else if (i < WS_WIH) v = W2[i - WS_W2];
    else if (i < WS_WHH) v = Wih[i - WS_WIH];
    else if (i < WS_WOUT) v = Whh[i - WS_WHH];
    else v = Wout[i - WS_WOUT];
    ws[i] = (bf16_t)v;
    if (i < Bb * NTILE) RA[i] = 0;
}

// =====================================================================
// pass1: one (4-batch x 16-step) tile per block. h_in = 0 guess (tile 0:
// real hx). Writes out rows (prefix rows garbage, fixed later), exit
// state E[b][tile] and has-init flag R[b][tile].
// LDS layout (bytes):
//   GX  0      bf16 [64][392] = 50176
//   HA  50176  bf16 [64][136] = 17408
//   HPB 67584  bf16 [2][16][136] = 8704
//   RED 76288  f32  [64][8] = 2048
//   MNR 78336  f32  [64][2] = 512
//   INI 78848  int  [4][17] = 272   -> total 79120 (2 blocks/CU)
// =====================================================================
#define P1_GX 0
#define P1_HA 50176
#define P1_HPB 67584
#define P1_RED 76288
#define P1_MNR 78336
#define P1_INI 78848
#define P1_SMEM 79120
#define BPB1 4

__global__ void __launch_bounds__(256, 2) gru_pass1(
    const float* __restrict__ x, const int* __restrict__ is_init,
    const float* __restrict__ hx,
    const float* __restrict__ b1, const float* __restrict__ g1, const float* __restrict__ be1,
    const float* __restrict__ b2, const float* __restrict__ g2, const float* __restrict__ be2,
    const float* __restrict__ bih, const float* __restrict__ bhh,
    const float* __restrict__ bout,
    const bf16_t* __restrict__ wsb,
    float* __restrict__ E, int* __restrict__ R,
    float* __restrict__ out)
{
    extern __shared__ char smem[];
    bf16_t* GX  = (bf16_t*)(smem + P1_GX);
    bf16_t* HA  = (bf16_t*)(smem + P1_HA);
    bf16_t* HPB = (bf16_t*)(smem + P1_HPB);
    float*  RED = (float*) (smem + P1_RED);
    float*  MNR = (float*) (smem + P1_MNR);
    int*    INI = (int*)   (smem + P1_INI);

    const bf16_t* W1B  = wsb + WS_W1;
    const bf16_t* W2B  = wsb + WS_W2;
    const bf16_t* WihB = wsb + WS_WIH;
    const bf16_t* WhhB = wsb + WS_WHH;
    const bf16_t* WoB  = wsb + WS_WOUT;

    const int tid  = threadIdx.x;
    const int w    = tid >> 6;
    const int lane = tid & 63;
    const int ln   = lane & 15;
    const int quad = lane >> 4;
    const int b0   = blockIdx.x * BPB1;
    const int tile = blockIdx.y;
    const int t0   = tile * CHUNK;

    for (int i = tid; i < 2 * 16 * HAS; i += 256) HPB[i] = (bf16_t)0.f;
    __syncthreads();

    // h_in: tile 0 -> real hx (with is_init[b,0] reset); else 0 guess.
    float hp[2] = {0.f, 0.f};
    if (tile == 0) {
        const int b = quad;   // quad = batch (rows b*4 in C)
        int im = is_init[(size_t)(b0 + b) * Tt];
#pragma unroll
        for (int sub = 0; sub < 2; ++sub) {
            int j = w * 32 + sub * 16 + ln;
            float v = im ? 0.f : hx[(size_t)(b0 + b) * H + j];
            hp[sub] = v;
            HPB[b * 4 * HAS + j] = (bf16_t)v;   // parity buffer 0 (t0 even)
        }
    }
    // hoist b_hh
    float bh[3][2];
#pragma unroll
    for (int g = 0; g < 3; ++g)
#pragma unroll
        for (int sub = 0; sub < 2; ++sub)
            bh[g][sub] = bhh[g * H + w * 32 + sub * 16 + ln];

    // hoist W_hh fragments (used 16x in the serial loop)
    bf16x8 whhf[6][4];
#pragma unroll
    for (int ntl = 0; ntl < 6; ++ntl) {
        int gate = ntl >> 1, sub = ntl & 1;
        int n = gate * H + w * 32 + sub * 16 + ln;
#pragma unroll
        for (int ks = 0; ks < 4; ++ks)
            whhf[ntl][ks] = *(const bf16x8*)(WhhB + (size_t)n * H + ks * 32 + quad * 8);
    }
    __syncthreads();

    // ============ phase A: MLP + gates for 64 rows (4b x 16t) ============
    f32x4 vs[BPB1][2];

    // ---- S1 ----
    {
        bf16x8 w1f[2][2];
#pragma unroll
        for (int ntl = 0; ntl < 2; ++ntl) {
            int n = w * 32 + ntl * 16 + ln;
#pragma unroll
            for (int ks = 0; ks < 2; ++ks)
                w1f[ntl][ks] = *(const bf16x8*)(W1B + (size_t)n * IN_DIM + ks * 32 + quad * 8);
        }
#pragma unroll
        for (int mt = 0; mt < BPB1; ++mt) {
            const float* xr_ = x + ((size_t)(b0 + mt) * Tt + t0 + ln) * IN_DIM;
            bf16x8 a0, a1;
#pragma unroll
            for (int j = 0; j < 8; ++j) {
                a0[j] = (bf16_t)xr_[quad * 8 + j];
                a1[j] = (bf16_t)xr_[32 + quad * 8 + j];
            }
#pragma unroll
            for (int ntl = 0; ntl < 2; ++ntl) {
                f32x4 c = {0.f, 0.f, 0.f, 0.f};
                c = MFMA(a0, w1f[ntl][0], c);
                c = MFMA(a1, w1f[ntl][1], c);
                vs[mt][ntl] = c;
            }
        }
        float bv[2], gv[2], bev[2];
#pragma unroll
        for (int ntl = 0; ntl < 2; ++ntl) {
            int n = w * 32 + ntl * 16 + ln;
            bv[ntl] = b1[n]; gv[ntl] = g1[n]; bev[ntl] = be1[n];
        }
#pragma unroll
        for (int mt = 0; mt < BPB1; ++mt) {
#pragma unroll
            for (int reg = 0; reg < 4; ++reg) {
                float v0 = vs[mt][0][reg] + bv[0]; v0 = v0 > 0.f ? v0 : NEG * v0;
                float v1 = vs[mt][1][reg] + bv[1]; v1 = v1 > 0.f ? v1 : NEG * v1;
                vs[mt][0][reg] = v0; vs[mt][1][reg] = v1;
                float s = v0 + v1, q = v0 * v0 + v1 * v1;
#pragma unroll
                for (int d = 1; d < 16; d <<= 1) { s += __shfl_xor(s, d); q += __shfl_xor(q, d); }
                if (ln == 0) {
                    int rr = mt * 16 + quad * 4 + reg;
                    RED[rr * 8 + w] = s; RED[rr * 8 + 4 + w] = q;
                }
            }
        }
        __syncthreads();
        if (tid < 64) {
            float s = RED[tid * 8] + RED[tid * 8 + 1] + RED[tid * 8 + 2] + RED[tid * 8 + 3];
            float q = RED[tid * 8 + 4] + RED[tid * 8 + 5] + RED[tid * 8 + 6] + RED[tid * 8 + 7];
            float mean = s * (1.f / H);
            float var = q * (1.f / H) - mean * mean;
            MNR[tid * 2] = mean; MNR[tid * 2 + 1] = rsqrtf(var + EPSLN);
        }
        __syncthreads();
#pragma unroll
        for (int mt = 0; mt < BPB1; ++mt) {
#pragma unroll
            for (int reg = 0; reg < 4; ++reg) {
                int rr = mt * 16 + quad * 4 + reg;
                float mean = MNR[rr * 2], rstd = MNR[rr * 2 + 1];
#pragma unroll
                for (int ntl = 0; ntl < 2; ++ntl) {
                    int n = w * 32 + ntl * 16 + ln;
                    HA[rr * HAS + n] = (bf16_t)(gv[ntl] * (vs[mt][ntl][reg] - mean) * rstd + bev[ntl]);
                }
            }
        }
        __syncthreads();
    }

    // ---- S2 ----
    {
        bf16x8 w2f[2][4];
#pragma unroll
        for (int ntl = 0; ntl < 2; ++ntl) {
            int n = w * 32 + ntl * 16 + ln;
#pragma unroll
            for (int ks = 0; ks < 4; ++ks)
                w2f[ntl][ks] = *(const bf16x8*)(W2B + (size_t)n * H + ks * 32 + quad * 8);
        }
#pragma unroll
        for (int mt = 0; mt < BPB1; ++mt) {
            bf16x8 af[4];
#pragma unroll
            for (int ks = 0; ks < 4; ++ks)
                af[ks] = *(const bf16x8*)(HA + (mt * 16 + ln) * HAS + ks * 32 + quad * 8);
#pragma unroll
            for (int ntl = 0; ntl < 2; ++ntl) {
                f32x4 c = {0.f, 0.f, 0.f, 0.f};
#pragma unroll
                for (int ks = 0; ks < 4; ++ks) c = MFMA(af[ks], w2f[ntl][ks], c);
                vs[mt][ntl] = c;
            }
        }
        float bv[2], gv[2], bev[2];
#pragma unroll
        for (int ntl = 0; ntl < 2; ++ntl) {
            int n = w * 32 + ntl * 16 + ln;
            bv[ntl] = b2[n]; gv[ntl] = g2[n]; bev[ntl] = be2[n];
        }
#pragma unroll
        for (int mt = 0; mt < BPB1; ++mt) {
#pragma unroll
            for (int reg = 0; reg < 4; ++reg) {
                float v0 = vs[mt][0][reg] + bv[0]; v0 = v0 > 0.f ? v0 : NEG * v0;
                float v1 = vs[mt][1][reg] + bv[1]; v1 = v1 > 0.f ? v1 : NEG * v1;
                vs[mt][0][reg] = v0; vs[mt][1][reg] = v1;
                float s = v0 + v1, q = v0 * v0 + v1 * v1;
#pragma unroll
                for (int d = 1; d < 16; d <<= 1) { s += __shfl_xor(s, d); q += __shfl_xor(q, d); }
                if (ln == 0) {
                    int rr = mt * 16 + quad * 4 + reg;
                    RED[rr * 8 + w] = s; RED[rr * 8 + 4 + w] = q;
                }
            }
        }
        __syncthreads();
        if (tid < 64) {
            float s = RED[tid * 8] + RED[tid * 8 + 1] + RED[tid * 8 + 2] + RED[tid * 8 + 3];
            float q = RED[tid * 8 + 4] + RED[tid * 8 + 5] + RED[tid * 8 + 6] + RED[tid * 8 + 7];
            float mean = s * (1.f / H);
            float var = q * (1.f / H) - mean * mean;
            MNR[tid * 2] = mean; MNR[tid * 2 + 1] = rsqrtf(var + EPSLN);
        }
        __syncthreads();
#pragma unroll
        for (int mt = 0; mt < BPB1; ++mt) {
#pragma unroll
            for (int reg = 0; reg < 4; ++reg) {
                int rr = mt * 16 + quad * 4 + reg;
                float mean = MNR[rr * 2], rstd = MNR[rr * 2 + 1];
#pragma unroll
                for (int ntl = 0; ntl < 2; ++ntl) {
                    int n = w * 32 + ntl * 16 + ln;
                    HA[rr * HAS + n] = (bf16_t)(gv[ntl] * (vs[mt][ntl][reg] - mean) * rstd + bev[ntl]);
                }
            }
        }
        __syncthreads();
    }

    // ---- S3: gx -> GX tile ----
#pragma unroll
    for (int half = 0; half < 2; ++half) {
        bf16x8 wf[3][4];
        float bv[3];
#pragma unroll
        for (int k3 = 0; k3 < 3; ++k3) {
            int n = (w * 6 + half * 3 + k3) * 16 + ln;
            bv[k3] = bih[n];
#pragma unroll
            for (int ks = 0; ks < 4; ++ks)
                wf[k3][ks] = *(const bf16x8*)(WihB + (size_t)n * H + ks * 32 + quad * 8);
        }
#pragma unroll
        for (int mt = 0; mt < BPB1; ++mt) {
            bf16x8 af[4];
#pragma unroll
            for (int ks = 0; ks < 4; ++ks)
                af[ks] = *(const bf16x8*)(HA + (mt * 16 + ln) * HAS + ks * 32 + quad * 8);
#pragma unroll
            for (int k3 = 0; k3 < 3; ++k3) {
                int n = (w * 6 + half * 3 + k3) * 16 + ln;
                f32x4 c = {0.f, 0.f, 0.f, 0.f};
#pragma unroll
                for (int ks = 0; ks < 4; ++ks) c = MFMA(af[ks], wf[k3][ks], c);
#pragma unroll
                for (int reg = 0; reg < 4; ++reg)
                    GX[(mt * 16 + quad * 4 + reg) * GXS + n] = (bf16_t)(c[reg] + bv[k3]);
            }
        }
    }
    if (tid < BPB1 * 17) {
        int b = tid / 17, s = tid % 17;
        int t = t0 + s;
        INI[tid] = (t < Tt) ? is_init[(size_t)(b0 + b) * Tt + t] : 0;
    }

    // ============ recurrent: 16 GRU steps, one barrier per step ==========
    for (int s = 0; s < CHUNK; ++s) {
        __syncthreads();
        const int t = t0 + s;
        const int rp = t & 1;
        bf16x8 af[4];
#pragma unroll
        for (int ks = 0; ks < 4; ++ks)
            af[ks] = *(const bf16x8*)(HPB + rp * 16 * HAS + ln * HAS + ks * 32 + quad * 8);
        f32x4 gc[6];
#pragma unroll
        for (int ntl = 0; ntl < 6; ++ntl) {
            f32x4 c = {0.f, 0.f, 0.f, 0.f};
#pragma unroll
            for (int ks = 0; ks < 4; ++ks) c = MFMA(af[ks], whhf[ntl][ks], c);
            gc[ntl] = c;
        }
        // batch b = quad at C-row b*4 (reg 0): in-register gate math.
        {
            const int b = quad;
            bf16_t* hw = HPB + (rp ^ 1) * 16 * HAS + b * 4 * HAS;
            const int rbase = (b * 16 + s) * GXS;
#pragma unroll
            for (int sub = 0; sub < 2; ++sub) {
                int j = w * 32 + sub * 16 + ln;
                float xr = (float)GX[rbase + j];
                float xz = (float)GX[rbase + H + j];
                float xn = (float)GX[rbase + 2 * H + j];
                float hr = gc[sub][0]     + bh[0][sub];
                float hz = gc[2 + sub][0] + bh[1][sub];
                float hn = gc[4 + sub][0] + bh[2][sub];
                float r = 1.f / (1.f + __expf(-(xr + hr)));
                float z = 1.f / (1.f + __expf(-(xz + hz)));
                float a = xn + r * hn;
                a = fminf(fmaxf(a, -15.f), 15.f);
                float e = __expf(-2.f * a);
                float nn = (1.f - e) / (1.f + e);
                float hnew = (1.f - z) * nn + z * hp[sub];
                HA[(b * 16 + s) * HAS + j] = (bf16_t)hnew;
                float hm;
                if (s < CHUNK - 1) {
                    hm = INI[b * 17 + s + 1] ? 0.f : hnew;   // fold next reset
                } else {
                    hm = hnew;                                // tile exit: no fold
                    E[((size_t)(b0 + b) * NTILE + tile) * H + j] = hnew;
                }
                hp[sub] = hm;
                hw[j] = (bf16_t)hm;
            }
        }
    }
    __syncthreads();

    // R flag: tile has an init? (tile 0 always exact)
    if (tid < BPB1) {
        int any = 0;
#pragma unroll
        for (int s = 0; s < CHUNK; ++s) any |= INI[tid * 17 + s];
        R[(b0 + tid) * NTILE + tile] = (tile == 0) ? 1 : (any ? 1 : 0);
    }

    // ============ out-projection ====================
    {
        int o = w * 16 + ln;
        bf16x8 wof[4];
#pragma unroll
        for (int ks = 0; ks < 4; ++ks)
            wof[ks] = *(const bf16x8*)(WoB + (size_t)o * H + ks * 32 + quad * 8);
        float bo = bout[o];
#pragma unroll
        for (int mt = 0; mt < BPB1; ++mt) {
            bf16x8 af[4];
#pragma unroll
            for (int ks = 0; ks < 4; ++ks)
                af[ks] = *(const bf16x8*)(HA + (mt * 16 + ln) * HAS + ks * 32 + quad * 8);
            f32x4 c = {0.f, 0.f, 0.f, 0.f};
#pragma unroll
            for (int ks = 0; ks < 4; ++ks) c = MFMA(af[ks], wof[ks], c);
#pragma unroll
            for (int reg = 0; reg < 4; ++reg)
                out[((size_t)(b0 + mt) * Tt + t0 + quad * 4 + reg) * OUT_DIM + o] = c[reg] + bo;
        }
    }
}

// =====================================================================
// fixp: for each (16-batch group, tile i>=1) whose predecessor tile is
// exact (R[i-1]=1), recompute the prefix steps (before first init) with
// the exact carry E[i-1]. M=16 rows = 16 batches (full MFMA usage).
// =====================================================================
__global__ void __launch_bounds__(256, 2) gru_fixp(
    const float* __restrict__ x, const int* __restrict__ is_init,
    const float* __restrict__ b1, const float* __restrict__ g1, const float* __restrict__ be1,
    const float* __restrict__ b2, const float* __restrict__ g2, const float* __restrict__ be2,
    const float* __restrict__ bih, const float* __restrict__ bhh,
    const float* __restrict__ bout,
    const bf16_t* __restrict__ wsb,
    float* __restrict__ E, const int* __restrict__ R, int* __restrict__ RA,
    float* __restrict__ out)
{
    __shared__ bf16_t sHA[16 * HAS];
    __shared__ bf16_t sHPB[2][16 * HAS];
    __shared__ float  sHPF[16 * 128];
    __shared__ float  sRED[16 * 8];
    __shared__ float  sMNR[16 * 2];
    __shared__ int    sINI[16 * 16];
    __shared__ int    sF[16];
    __shared__ int    sNeed[16];
    __shared__ int    sAny, sMaxf;

    const bf16_t* W1B  = wsb + WS_W1;
    const bf16_t* W2B  = wsb + WS_W2;
    const bf16_t* WihB = wsb + WS_WIH;
    const bf16_t* WhhB = wsb + WS_WHH;
    const bf16_t* WoB  = wsb + WS_WOUT;

    const int tid  = threadIdx.x;
    const int w    = tid >> 6;
    const int lane = tid & 63;
    const int ln   = lane & 15;
    const int quad = lane >> 4;
    const int bB   = blockIdx.x * 16;
    const int i    = blockIdx.y + 1;
    const int t0   = i * CHUNK;

    {
        int b = tid >> 4, s = tid & 15;
        sINI[tid] = is_init[(size_t)(bB + b) * Tt + t0 + s];
    }
    if (tid < 16) sNeed[tid] = R[(bB + tid) * NTILE + (i - 1)];
    if (tid == 0) { sAny = 0; sMaxf = 0; }
    __syncthreads();
    if (tid < 16) {
        int f = 16;
        for (int s = 15; s >= 0; --s) if (sINI[tid * 16 + s]) f = s;
        sF[tid] = f;
        int need = (sNeed[tid] && f > 0) ? 1 : 0;
        sNeed[tid] = need;
        if (need) { atomicOr(&sAny, 1); atomicMax(&sMaxf, f); }
    }
    __syncthreads();
    if (!sAny) return;
    const int maxf = sMaxf;

    // init carry: h_prev = E[b][i-1] for needy batches
    for (int idx = tid; idx < 16 * 128; idx += 256) {
        int b = idx >> 7, j = idx & 127;
        float v = sNeed[b] ? E[((size_t)(bB + b) * NTILE + i - 1) * H + j] : 0.f;
        sHPF[idx] = v;
        sHPB[0][b * HAS + j] = (bf16_t)v;
        sHPB[1][b * HAS + j] = (bf16_t)0.f;
    }

    // hoisted constants
    float bh[3][2], bihv[6];
#pragma unroll
    for (int g = 0; g < 3; ++g)
#pragma unroll
        for (int sub = 0; sub < 2; ++sub) {
            int j = w * 32 + sub * 16 + ln;
            bh[g][sub] = bhh[g * H + j];
            bihv[g * 2 + sub] = bih[g * H + j];
        }
    float bv1[2], gv1[2], bev1[2], bv2[2], gv2[2], bev2[2];
#pragma unroll
    for (int ntl = 0; ntl < 2; ++ntl) {
        int n = w * 32 + ntl * 16 + ln;
        bv1[ntl] = b1[n]; gv1[ntl] = g1[n]; bev1[ntl] = be1[n];
        bv2[ntl] = b2[n]; gv2[ntl] = g2[n]; bev2[ntl] = be2[n];
    }
    bf16x8 whhf[6][4];
#pragma unroll
    for (int ntl = 0; ntl < 6; ++ntl) {
        int gate = ntl >> 1, sub = ntl & 1;
        int n = gate * H + w * 32 + sub * 16 + ln;
#pragma unroll
        for (int ks = 0; ks < 4; ++ks)
            whhf[ntl][ks] = *(const bf16x8*)(WhhB + (size_t)n * H + ks * 32 + quad * 8);
    }
    bf16x8 wof[4];
    {
        int o = w * 16 + ln;
#pragma unroll
        for (int ks = 0; ks < 4; ++ks)
            wof[ks] = *(const bf16x8*)(WoB + (size_t)o * H + ks * 32 + quad * 8);
    }
    float bo = bout[w * 16 + ln];
    __syncthreads();

    for (int s = 0; s < maxf; ++s) {
        const int t = t0 + s;
        const int par = s & 1;
        f32x4 vs[2];

        // ---- S1 (rows = 16 batches, one timestep t) ----
        {
            const float* xr_ = x + ((size_t)(bB + ln) * Tt + t) * IN_DIM;
            bf16x8 a0, a1;
#pragma unroll
            for (int j = 0; j < 8; ++j) {
                a0[j] = (bf16_t)xr_[quad * 8 + j];
                a1[j] = (bf16_t)xr_[32 + quad * 8 + j];
            }
#pragma unroll
            for (int ntl = 0; ntl < 2; ++ntl) {
                int n = w * 32 + ntl * 16 + ln;
                bf16x8 f0 = *(const bf16x8*)(W1B + (size_t)n * IN_DIM + quad * 8);
                bf16x8 f1 = *(const bf16x8*)(W1B + (size_t)n * IN_DIM + 32 + quad * 8);
                f32x4 c = {0.f, 0.f, 0.f, 0.f};
                c = MFMA(a0, f0, c);
                c = MFMA(a1, f1, c);
                vs[ntl] = c;
            }
        }
#pragma unroll
        for (int reg = 0; reg < 4; ++reg) {
            float v0 = vs[0][reg] + bv1[0]; v0 = v0 > 0.f ? v0 : NEG * v0;
            float v1 = vs[1][reg] + bv1[1]; v1 = v1 > 0.f ? v1 : NEG * v1;
            vs[0][reg] = v0; vs[1][reg] = v1;
            float sm = v0 + v1, q = v0 * v0 + v1 * v1;
#pragma unroll
            for (int d = 1; d < 16; d <<= 1) { sm += __shfl_xor(sm, d); q += __shfl_xor(q, d); }
            if (ln == 0) {
                int rr = quad * 4 + reg;
                sRED[rr * 8 + w] = sm; sRED[rr * 8 + 4 + w] = q;
            }
        }
        __syncthreads();
        if (tid < 16) {
            float sm = sRED[tid * 8] + sRED[tid * 8 + 1] + sRED[tid * 8 + 2] + sRED[tid * 8 + 3];
            float q = sRED[tid * 8 + 4] + sRED[tid * 8 + 5] + sRED[tid * 8 + 6] + sRED[tid * 8 + 7];
            float mean = sm * (1.f / H);
            float var = q * (1.f / H) - mean * mean;
            sMNR[tid * 2] = mean; sMNR[tid * 2 + 1] = rsqrtf(var + EPSLN);
        }
        __syncthreads();
#pragma unroll
        for (int reg = 0; reg < 4; ++reg) {
            int rr = quad * 4 + reg;
            float mean = sMNR[rr * 2], rstd = sMNR[rr * 2 + 1];
#pragma unroll
            for (int ntl = 0; ntl < 2; ++ntl) {
                int n = w * 32 + ntl * 16 + ln;
                sHA[rr * HAS + n] = (bf16_t)(gv1[ntl] * (vs[ntl][reg] - mean) * rstd + bev1[ntl]);
            }
        }
        __syncthreads();

        // ---- S2 ----
        {
            bf16x8 af[4];
#pragma unroll
            for (int ks = 0; ks < 4; ++ks)
                af[ks] = *(const bf16x8*)(sHA + ln * HAS + ks * 32 + quad * 8);
#pragma unroll
            for (int ntl = 0; ntl < 2; ++ntl) {
                int n = w * 32 + ntl * 16 + ln;
                f32x4 c = {0.f, 0.f, 0.f, 0.f};
#pragma unroll
                for (int ks = 0; ks < 4; ++ks) {
                    bf16x8 f = *(const bf16x8*)(W2B + (size_t)n * H + ks * 32 + quad * 8);
                    c = MFMA(af[ks], f, c);
                }
                vs[ntl] = c;
            }
        }
        __syncthreads();   // all sHA(h1) reads done before overwrite
#pragma unroll
        for (int reg = 0; reg < 4; ++reg) {
            float v0 = vs[0][reg] + bv2[0]; v0 = v0 > 0.f ? v0 : NEG * v0;
            float v1 = vs[1][reg] + bv2[1]; v1 = v1 > 0.f ? v1 : NEG * v1;
            vs[0][reg] = v0; vs[1][reg] = v1;
            float sm = v0 + v1, q = v0 * v0 + v1 * v1;
#pragma unroll
            for (int d = 1; d < 16; d <<= 1) { sm += __shfl_xor(sm, d); q += __shfl_xor(q, d); }
            if (ln == 0) {
                int rr = quad * 4 + reg;
                sRED[rr * 8 + w] = sm; sRED[rr * 8 + 4 + w] = q;
            }
        }
        __syncthreads();
        if (tid < 16) {
            float sm = sRED[tid * 8] + sRED[tid * 8 + 1] + sRED[tid * 8 + 2] + sRED[tid * 8 + 3];
            float q = sRED[tid * 8 + 4] + sRED[tid * 8 + 5] + sRED[tid * 8 + 6] + sRED[tid * 8 + 7];
            float mean = sm * (1.f / H);
            float var = q * (1.f / H) - mean * mean;
            sMNR[tid * 2] = mean; sMNR[tid * 2 + 1] = rsqrtf(var + EPSLN);
        }
        __syncthreads();
#pragma unroll
        for (int reg = 0; reg < 4; ++reg) {
            int rr = quad * 4 + reg;
            float mean = sMNR[rr * 2], rstd = sMNR[rr * 2 + 1];
#pragma unroll
            for (int ntl = 0; ntl < 2; ++ntl) {
                int n = w * 32 + ntl * 16 + ln;
                sHA[rr * HAS + n] = (bf16_t)(gv2[ntl] * (vs[ntl][reg] - mean) * rstd + bev2[ntl]);
            }
        }
        __syncthreads();

        // ---- gx (streamed Wih) + gh (hoisted Whh) ----
        bf16x8 af2[4], afh[4];
#pragma unroll
        for (int ks = 0; ks < 4; ++ks) {
            af2[ks] = *(const bf16x8*)(sHA + ln * HAS + ks * 32 + quad * 8);
            afh[ks] = *(const bf16x8*)(sHPB[par] + ln * HAS + ks * 32 + quad * 8);
        }
        f32x4 gxc[6], ghc[6];
#pragma unroll
        for (int ntl = 0; ntl < 6; ++ntl) {
            int gate = ntl >> 1, sub = ntl & 1;
            int n = gate * H + w * 32 + sub * 16 + ln;
            f32x4 cg = {0.f, 0.f, 0.f, 0.f};
#pragma unroll
            for (int ks = 0; ks < 4; ++ks) {
                bf16x8 f = *(const bf16x8*)(WihB + (size_t)n * H + ks * 32 + quad * 8);
                cg = MFMA(af2[ks], f, cg);
            }
            gxc[ntl] = cg;
            f32x4 ch = {0.f, 0.f, 0.f, 0.f};
#pragma unroll
            for (int ks = 0; ks < 4; ++ks) ch = MFMA(afh[ks], whhf[ntl][ks], ch);
            ghc[ntl] = ch;
        }
        __syncthreads();   // all sHA(h2)/sHPB reads done

        // ---- gate math: lane handles batches quad*4+reg, cols j ----
#pragma unroll
        for (int reg = 0; reg < 4; ++reg) {
            const int b = quad * 4 + reg;
            const int msk = sNeed[b] && (s < sF[b]);
#pragma unroll
            for (int sub = 0; sub < 2; ++sub) {
                int j = w * 32 + sub * 16 + ln;
                float xr = gxc[sub][reg]     + bihv[sub];
                float xz = gxc[2 + sub][reg] + bihv[2 + sub];
                float xn = gxc[4 + sub][reg] + bihv[4 + sub];
                float hr = ghc[sub][reg]     + bh[0][sub];
                float hz = ghc[2 + sub][reg] + bh[1][sub];
                float hn = ghc[4 + sub][reg] + bh[2][sub];
                float r = 1.f / (1.f + __expf(-(xr + hr)));
                float z = 1.f / (1.f + __expf(-(xz + hz)));
                float a = xn + r * hn;
                a = fminf(fmaxf(a, -15.f), 15.f);
                float e = __expf(-2.f * a);
                float nn = (1.f - e) / (1.f + e);
                float hp = sHPF[b * 128 + j];
                float hnew = (1.f - z) * nn + z * hp;
                if (msk) {
                    sHPF[b * 128 + j] = hnew;
                    sHPB[par ^ 1][b * HAS + j] = (bf16_t)hnew;
                    sHA[b * HAS + j] = (bf16_t)hnew;   // y row
                }
            }
        }
        __syncthreads();

        // ---- out-projection (masked rows) ----
        {
            bf16x8 af[4];
#pragma unroll
            for (int ks = 0; ks < 4; ++ks)
                af[ks] = *(const bf16x8*)(sHA + ln * HAS + ks * 32 + quad * 8);
            f32x4 c = {0.f, 0.f, 0.f, 0.f};
#pragma unroll
            for (int ks = 0; ks < 4; ++ks) c = MFMA(af[ks], wof[ks], c);
            int o = w * 16 + ln;
#pragma unroll
            for (int reg = 0; reg < 4; ++reg) {
                int b = quad * 4 + reg;
                if (sNeed[b] && s < sF[b])
                    out[((size_t)(bB + b) * Tt + t) * OUT_DIM + o] = c[reg] + bo;
            }
        }
        __syncthreads();
    }

    // init-free tiles: write recomputed exit + R_A
    for (int idx = tid; idx < 16 * 128; idx += 256) {
        int b = idx >> 7, j = idx & 127;
        if (sNeed[b] && sF[b] == 16)
            E[((size_t)(bB + b) * NTILE + i) * H + j] = sHPF[b * 128 + j];
    }
    if (tid < 16 && sNeed[tid] && sF[tid] == 16)
        RA[(bB + tid) * NTILE + i] = 1;
}

// =====================================================================
// sweeper: per-batch sequential resolution of tiles whose predecessor
// was NOT exact after pass1 (rare), + writes hx_final. f32 VALU path.
// =====================================================================
__global__ void __launch_bounds__(128) gru_sweep(
    const float* __restrict__ x, const int* __restrict__ is_init,
    const float* __restrict__ W1, const float* __restrict__ b1,
    const float* __restrict__ g1, const float* __restrict__ be1,
    const float* __restrict__ W2, const float* __restrict__ b2,
    const float* __restrict__ g2, const float* __restrict__ be2,
    const float* __restrict__ Wih, const float* __restrict__ Whh,
    const float* __restrict__ bih, const float* __restrict__ bhh,
    const float* __restrict__ Wout, const float* __restrict__ bout,
    const float* __restrict__ E, const int* __restrict__ R, const int* __restrict__ RA,
    float* __restrict__ out)
{
    __shared__ float sX[64], sH1[128], sH2[128], sHH[128], sRS[4];
    __shared__ int sI[16], sFf;

    const int b = blockIdx.x;
    const int j = threadIdx.x;      // 0..127
    const int wv = j >> 6, lj = j & 63;

    float h = E[((size_t)b * NTILE) * H + j];

    for (int i = 1; i < NTILE; ++i) {
        int Rm1 = R[b * NTILE + i - 1];
        if (!Rm1) {
            if (j < 16) sI[j] = is_init[(size_t)b * Tt + i * CHUNK + j];
            __syncthreads();
            if (j == 0) {
                int f = 16;
                for (int s = 15; s >= 0; --s) if (sI[s]) f = s;
                sFf = f;
            }
            __syncthreads();
            int f = sFf;
            for (int s = 0; s < f; ++s) {
                int t = i * CHUNK + s;
                sHH[j] = h;
                if (j < 64) sX[j] = x[((size_t)b * Tt + t) * IN_DIM + j];
                __syncthreads();
                // h1
                float a1 = b1[j];
                const float* w1r = W1 + (size_t)j * IN_DIM;
                for (int k = 0; k < 64; ++k) a1 += sX[k] * w1r[k];
                a1 = a1 > 0.f ? a1 : NEG * a1;
                {
                    float sv = a1, sq = a1 * a1;
                    for (int d = 1; d < 64; d <<= 1) { sv += __shfl_xor(sv, d); sq += __shfl_xor(sq, d); }
                    if (lj == 0) { sRS[wv * 2] = sv; sRS[wv * 2 + 1] = sq; }
                    __syncthreads();
                    float mean = (sRS[0] + sRS[2]) * (1.f / H);
                    float var = (sRS[1] + sRS[3]) * (1.f / H) - mean * mean;
                    a1 = g1[j] * (a1 - mean) * rsqrtf(var + EPSLN) + be1[j];
                }
                sH1[j] = a1;
                __syncthreads();
                // h2
                float a2 = b2[j];
                const float* w2r = W2 + (size_t)j * H;
                for (int k = 0; k < 128; ++k) a2 += sH1[k] * w2r[k];
                a2 = a2 > 0.f ? a2 : NEG * a2;
                {
                    float sv = a2, sq = a2 * a2;
                    for (int d = 1; d < 64; d <<= 1) { sv += __shfl_xor(sv, d); sq += __shfl_xor(sq, d); }
                    if (lj == 0) { sRS[wv * 2] = sv; sRS[wv * 2 + 1] = sq; }
                    __syncthreads();
                    float mean = (sRS[0] + sRS[2]) * (1.f / H);
                    float var = (sRS[1] + sRS[3]) * (1.f / H) - mean * mean;
                    a2 = g2[j] * (a2 - mean) * rsqrtf(var + EPSLN) + be2[j];
                }
                sH2[j] = a2;
                __syncthreads();
                // gates
                float gx0 = bih[j], gx1 = bih[H + j], gx2 = bih[2 * H + j];
                float gh0 = bhh[j], gh1 = bhh[H + j], gh2 = bhh[2 * H + j];
                const float* wi0 = Wih + (size_t)j * H;
                const float* wi1 = Wih + (size_t)(H + j) * H;
                const float* wi2 = Wih + (size_t)(2 * H + j) * H;
                const float* wh0 = Whh + (size_t)j * H;
                const float* wh1 = Whh + (size_t)(H + j) * H;
                const float* wh2 = Whh + (size_t)(2 * H + j) * H;
                for (int k = 0; k < 128; ++k) {
                    float h2k = sH2[k], hhk = sHH[k];
                    gx0 += h2k * wi0[k]; gx1 += h2k * wi1[k]; gx2 += h2k * wi2[k];
                    gh0 += hhk * wh0[k]; gh1 += hhk * wh1[k]; gh2 += hhk * wh2[k];
                }
                float r = 1.f / (1.f + __expf(-(gx0 + gh0)));
                float z = 1.f / (1.f + __expf(-(gx1 + gh1)));
                float a = gx2 + r * gh2;
                a = fminf(fmaxf(a, -15.f), 15.f);
                float e = __expf(-2.f * a);
                float nn = (1.f - e) / (1.f + e);
                h = (1.f - z) * nn + z * h;
                __syncthreads();
                sH1[j] = h;   // reuse as y
                __syncthreads();
                if (j < 64) {
                    float o = bout[j];
                    const float* wo = Wout + (size_t)j * H;
                    for (int k = 0; k < 128; ++k) o += sH1[k] * wo[k];
                    out[((size_t)b * Tt + t) * OUT_DIM + j] = o;
                }
                __syncthreads();
            }
            if (f < 16) h = E[((size_t)b * NTILE + i) * H + j];   // R[i]==1
            // else: h stays recomputed (full-tile)
        } else {
            if (R[b * NTILE + i] || RA[b * NTILE + i])
                h = E[((size_t)b * NTILE + i) * H + j];
            // else impossible: fixp ran for (b,i) and set RA when no init
        }
    }
    out[(size_t)Bb * Tt * OUT_DIM + (size_t)b * H + j] = h;
}

// =====================================================================
// fallback (ws too small): round-1 monolithic sequential kernel, f32.
// =====================================================================
#define FGX_OFF 0
#define FHA_OFF 25088
#define FHPB_OFF 33792
#define FRED_OFF 42496
#define FMNR_OFF 43520
#define FVEC_OFF 43776
#define FINI_OFF 50176
#define FSMEM 50320
#define FV_B1 0
#define FV_G1 128
#define FV_BE1 256
#define FV_B2 384
#define FV_G2 512
#define FV_BE2 640
#define FV_BIH 768
#define FV_BHH 1152
#define FV_BOUT 1536

__global__ void __launch_bounds__(256, 2) gru_seq(
    const float* __restrict__ x, const int* __restrict__ is_init,
    const float* __restrict__ hx,
    const float* __restrict__ W1, const float* __restrict__ b1,
    const float* __restrict__ g1, const float* __restrict__ be1,
    const float* __restrict__ W2, const float* __restrict__ b2,
    const float* __restrict__ g2, const float* __restrict__ be2,
    const float* __restrict__ Wih, const float* __restrict__ Whh,
    const float* __restrict__ bih, const float* __restrict__ bhh,
    const float* __restrict__ Wout, const float* __restrict__ bout,
    float* __restrict__ out)
{
    extern __shared__ char smem[];
    bf16_t* GX  = (bf16_t*)(smem + FGX_OFF);
    bf16_t* HA  = (bf16_t*)(smem + FHA_OFF);
    bf16_t* HPB = (bf16_t*)(smem + FHPB_OFF);
    float*  RED = (float*) (smem + FRED_OFF);
    float*  MNR = (float*) (smem + FMNR_OFF);
    float*  VEC = (float*) (smem + FVEC_OFF);
    int*    INI = (int*)   (smem + FINI_OFF);

    const int tid  = threadIdx.x;
    const int w    = tid >> 6;
    const int lane = tid & 63;
    const int ln   = lane & 15;
    const int quad = lane >> 4;
    const int b0   = blockIdx.x * 2;

    for (int i = tid; i < H; i += 256) {
        VEC[FV_B1 + i] = b1[i];  VEC[FV_G1 + i] = g1[i];  VEC[FV_BE1 + i] = be1[i];
        VEC[FV_B2 + i] = b2[i];  VEC[FV_G2 + i] = g2[i];  VEC[FV_BE2 + i] = be2[i];
    }
    for (int i = tid; i < G3; i += 256) {
        VEC[FV_BIH + i] = bih[i];  VEC[FV_BHH + i] = bhh[i];
    }
    if (tid < OUT_DIM) VEC[FV_BOUT + tid] = bout[tid];
    for (int i = tid; i < 2 * 16 * HAS; i += 256) HPB[i] = (bf16_t)0.f;
    __syncthreads();

    float hp[2] = {0.f, 0.f};
    if (quad < 2) {
        int b = quad;
        int im = is_init[(size_t)(b0 + b) * Tt];
#pragma unroll
        for (int sub = 0; sub < 2; ++sub) {
            int jj = w * 32 + sub * 16 + ln;
            float v = im ? 0.f : hx[(size_t)(b0 + b) * H + jj];
            hp[sub] = v;
            HPB[b * 4 * HAS + jj] = (bf16_t)v;
        }
    }
    float bh[3][2];
#pragma unroll
    for (int g = 0; g < 3; ++g)
#pragma unroll
        for (int sub = 0; sub < 2; ++sub)
            bh[g][sub] = bhh[g * H + w * 32 + sub * 16 + ln];

    bf16x8 whhf[6][4];
#pragma unroll
    for (int ntl = 0; ntl < 6; ++ntl) {
        int gate = ntl >> 1, sub = ntl & 1;
        int n = gate * H + w * 32 + sub * 16 + ln;
        const float* p = Whh + (size_t)n * H;
#pragma unroll
        for (int ks = 0; ks < 4; ++ks) {
            const float* q = p + ks * 32 + quad * 8;
            bf16x8 f;
#pragma unroll
            for (int jj = 0; jj < 8; ++jj) f[jj] = (bf16_t)q[jj];
            whhf[ntl][ks] = f;
        }
    }
    __syncthreads();

    for (int tc = 0; tc < NTILE; ++tc) {
        const int t0 = tc * CHUNK;
        f32x4 vs[2][2];
        {
            bf16x8 w1f[2][2];
#pragma unroll
            for (int ntl = 0; ntl < 2; ++ntl) {
                int n = w * 32 + ntl * 16 + ln;
                const float* p = W1 + (size_t)n * IN_DIM;
#pragma unroll
                for (int ks = 0; ks < 2; ++ks) {
                    const float* q = p + ks * 32 + quad * 8;
                    bf16x8 f;
#pragma unroll
                    for (int jj = 0; jj < 8; ++jj) f[jj] = (bf16_t)q[jj];
                    w1f[ntl][ks] = f;
                }
            }
#pragma unroll
            for (int mt = 0; mt < 2; ++mt) {
                const float* xr_ = x + ((size_t)(b0 + mt) * Tt + t0 + ln) * IN_DIM;
                bf16x8 a0, a1;
#pragma unroll
                for (int jj = 0; jj < 8; ++jj) {
                    a0[jj] = (bf16_t)xr_[quad * 8 + jj];
                    a1[jj] = (bf16_t)xr_[32 + quad * 8 + jj];
                }
#pragma unroll
                for (int ntl = 0; ntl < 2; ++ntl) {
                    f32x4 c = {0.f, 0.f, 0.f, 0.f};
                    c = MFMA(a0, w1f[ntl][0], c);
                    c = MFMA(a1, w1f[ntl][1], c);
                    vs[mt][ntl] = c;
                }
            }
            float bv[2], gv[2], bev[2];
#pragma unroll
            for (int ntl = 0; ntl < 2; ++ntl) {
                int n = w * 32 + ntl * 16 + ln;
                bv[ntl] = VEC[FV_B1 + n]; gv[ntl] = VEC[FV_G1 + n]; bev[ntl] = VEC[FV_BE1 + n];
            }
#pragma unroll
            for (int mt = 0; mt < 2; ++mt) {
#pragma unroll
                for (int reg = 0; reg < 4; ++reg) {
                    float v0 = vs[mt][0][reg] + bv[0]; v0 = v0 > 0.f ? v0 : NEG * v0;
                    float v1 = vs[mt][1][reg] + bv[1]; v1 = v1 > 0.f ? v1 : NEG * v1;
                    vs[mt][0][reg] = v0; vs[mt][1][reg] = v1;
                    float s = v0 + v1, q = v0 * v0 + v1 * v1;
#pragma unroll
                    for (int d = 1; d < 16; d <<= 1) { s += __shfl_xor(s, d); q += __shfl_xor(q, d); }
                    if (ln == 0) {
                        int rr = mt * 16 + quad * 4 + reg;
                        RED[rr * 8 + w] = s; RED[rr * 8 + 4 + w] = q;
                    }
                }
            }
            __syncthreads();
            if (tid < 32) {
                float s = RED[tid * 8] + RED[tid * 8 + 1] + RED[tid * 8 + 2] + RED[tid * 8 + 3];
                float q = RED[tid * 8 + 4] + RED[tid * 8 + 5] + RED[tid * 8 + 6] + RED[tid * 8 + 7];
                float mean = s * (1.f / H);
                float var = q * (1.f / H) - mean * mean;
                MNR[tid * 2] = mean; MNR[tid * 2 + 1] = rsqrtf(var + EPSLN);
            }
            __syncthreads();
#pragma unroll
            for (int mt = 0; mt < 2; ++mt) {
#pragma unroll
                for (int reg = 0; reg < 4; ++reg) {
                    int rr = mt * 16 + quad * 4 + reg;
                    float mean = MNR[rr * 2], rstd = MNR[rr * 2 + 1];
#pragma unroll
                    for (int ntl = 0; ntl < 2; ++ntl) {
                        int n = w * 32 + ntl * 16 + ln;
                        HA[rr * HAS + n] = (bf16_t)(gv[ntl] * (vs[mt][ntl][reg] - mean) * rstd + bev[ntl]);
                    }
                }
            }
            __syncthreads();
        }
        {
            bf16x8 w2f[2][4];
#pragma unroll
            for (int ntl = 0; ntl < 2; ++ntl) {
                int n = w * 32 + ntl * 16 + ln;
                const float* p = W2 + (size_t)n * H;
#pragma unroll
                for (int ks = 0; ks < 4; ++ks) {
                    const float* q = p + ks * 32 + quad * 8;
                    bf16x8 f;
#pragma unroll
                    for (int jj = 0; jj < 8; ++jj) f[jj] = (bf16_t)q[jj];
                    w2f[ntl][ks] = f;
                }
            }
#pragma unroll
            for (int mt = 0; mt < 2; ++mt) {
                bf16x8 af[4];
#pragma unroll
                for (int ks = 0; ks < 4; ++ks)
                    af[ks] = *(const bf16x8*)(HA + (mt * 16 + ln) * HAS + ks * 32 + quad * 8);
#pragma unroll
                for (int ntl = 0; ntl < 2; ++ntl) {
                    f32x4 c = {0.f, 0.f, 0.f, 0.f};
#pragma unroll
                    for (int ks = 0; ks < 4; ++ks) c = MFMA(af[ks], w2f[ntl][ks], c);
                    vs[mt][ntl] = c;
                }
            }
            float bv[2], gv[2], bev[2];
#pragma unroll
            for (int ntl = 0; ntl < 2; ++ntl) {
                int n = w * 32 + ntl * 16 + ln;
                bv[ntl] = VEC[FV_B2 + n]; gv[ntl] = VEC[FV_G2 + n]; bev[ntl] = VEC[FV_BE2 + n];
            }
#pragma unroll
            for (int mt = 0; mt < 2; ++mt) {
#pragma unroll
                for (int reg = 0; reg < 4; ++reg) {
                    float v0 = vs[mt][0][reg] + bv[0]; v0 = v0 > 0.f ? v0 : NEG * v0;
                    float v1 = vs[mt][1][reg] + bv[1]; v1 = v1 > 0.f ? v1 : NEG * v1;
                    vs[mt][0][reg] = v0; vs[mt][1][reg] = v1;
                    float s = v0 + v1, q = v0 * v0 + v1 * v1;
#pragma unroll
                    for (int d = 1; d < 16; d <<= 1) { s += __shfl_xor(s, d); q += __shfl_xor(q, d); }
                    if (ln == 0) {
                        int rr = mt * 16 + quad * 4 + reg;
                        RED[rr * 8 + w] = s; RED[rr * 8 + 4 + w] = q;
                    }
                }
            }
            __syncthreads();
            if (tid < 32) {
                float s = RED[tid * 8] + RED[tid * 8 + 1] + RED[tid * 8 + 2] + RED[tid * 8 + 3];
                float q = RED[tid * 8 + 4] + RED[tid * 8 + 5] + RED[tid * 8 + 6] + RED[tid * 8 + 7];
                float mean = s * (1.f / H);
                float var = q * (1.f / H) - mean * mean;
                MNR[tid * 2] = mean; MNR[tid * 2 + 1] = rsqrtf(var + EPSLN);
            }
            __syncthreads();
#pragma unroll
            for (int mt = 0; mt < 2; ++mt) {
#pragma unroll
                for (int reg = 0; reg < 4; ++reg) {
                    int rr = mt * 16 + quad * 4 + reg;
                    float mean = MNR[rr * 2], rstd = MNR[rr * 2 + 1];
#pragma unroll
                    for (int ntl = 0; ntl < 2; ++ntl) {
                        int n = w * 32 + ntl * 16 + ln;
                        HA[rr * HAS + n] = (bf16_t)(gv[ntl] * (vs[mt][ntl][reg] - mean) * rstd + bev[ntl]);
                    }
                }
            }
            __syncthreads();
        }
#pragma unroll
        for (int half = 0; half < 2; ++half) {
            bf16x8 wf[3][4];
            float bv[3];
#pragma unroll
            for (int k3 = 0; k3 < 3; ++k3) {
                int n = (w * 6 + half * 3 + k3) * 16 + ln;
                bv[k3] = VEC[FV_BIH + n];
                const float* p = Wih + (size_t)n * H;
#pragma unroll
                for (int ks = 0; ks < 4; ++ks) {
                    const float* q = p + ks * 32 + quad * 8;
                    bf16x8 f;
#pragma unroll
                    for (int jj = 0; jj < 8; ++jj) f[jj] = (bf16_t)q[jj];
                    wf[k3][ks] = f;
                }
            }
#pragma unroll
            for (int mt = 0; mt < 2; ++mt) {
                bf16x8 af[4];
#pragma unroll
                for (int ks = 0; ks < 4; ++ks)
                    af[ks] = *(const bf16x8*)(HA + (mt * 16 + ln) * HAS + ks * 32 + quad * 8);
#pragma unroll
                for (int k3 = 0; k3 < 3; ++k3) {
                    int n = (w * 6 + half * 3 + k3) * 16 + ln;
                    f32x4 c = {0.f, 0.f, 0.f, 0.f};
#pragma unroll
                    for (int ks = 0; ks < 4; ++ks) c = MFMA(af[ks], wf[k3][ks], c);
#pragma unroll
                    for (int reg = 0; reg < 4; ++reg)
                        GX[(mt * 16 + quad * 4 + reg) * GXS + n] = (bf16_t)(c[reg] + bv[k3]);
                }
            }
        }
        if (tid < 2 * 17) {
            int b = tid / 17, s = tid % 17;
            int t = t0 + s;
            INI[tid] = (t < Tt) ? is_init[(size_t)(b0 + b) * Tt + t] : 0;
        }
        for (int s = 0; s < CHUNK; ++s) {
            __syncthreads();
            const int t = t0 + s;
            const int rp = t & 1;
            bf16x8 af[4];
#pragma unroll
            for (int ks = 0; ks < 4; ++ks)
                af[ks] = *(const bf16x8*)(HPB + rp * 16 * HAS + ln * HAS + ks * 32 + quad * 8);
            f32x4 gc[6];
#pragma unroll
            for (int ntl = 0; ntl < 6; ++ntl) {
                f32x4 c = {0.f, 0.f, 0.f, 0.f};
#pragma unroll
                for (int ks = 0; ks < 4; ++ks) c = MFMA(af[ks], whhf[ntl][ks], c);
                gc[ntl] = c;
            }
            if (quad < 2) {
                const int b = quad;
                bf16_t* hw = HPB + (rp ^ 1) * 16 * HAS + b * 4 * HAS;
                const int rbase = (b * 16 + s) * GXS;
#pragma unroll
                for (int sub = 0; sub < 2; ++sub) {
                    int jj = w * 32 + sub * 16 + ln;
                    float xr = (float)GX[rbase + jj];
                    float xz = (float)GX[rbase + H + jj];
                    float xn = (float)GX[rbase + 2 * H + jj];
                    float hr = gc[sub][0]     + bh[0][sub];
                    float hz = gc[2 + sub][0] + bh[1][sub];
                    float hn = gc[4 + sub][0] + bh[2][sub];
                    float r = 1.f / (1.f + __expf(-(xr + hr)));
                    float z = 1.f / (1.f + __expf(-(xz + hz)));
                    float a = xn + r * hn;
                    a = fminf(fmaxf(a, -15.f), 15.f);
                    float e = __expf(-2.f * a);
                    float nn = (1.f - e) / (1.f + e);
                    float hnew = (1.f - z) * nn + z * hp[sub];
                    HA[(b * 16 + s) * HAS + jj] = (bf16_t)hnew;
                    float hm;
                    if (t < Tt - 1) {
                        hm = INI[b * 17 + s + 1] ? 0.f : hnew;
                    } else {
                        hm = hnew;
                        out[(size_t)Bb * Tt * OUT_DIM + (size_t)(b0 + b) * H + jj] = hnew;
                    }
                    hp[sub] = hm;
                    hw[jj] = (bf16_t)hm;
                }
            }
        }
        __syncthreads();
        {
            int o = w * 16 + ln;
            const float* p = Wout + (size_t)o * H;
            bf16x8 wof[4];
#pragma unroll
            for (int ks = 0; ks < 4; ++ks) {
                const float* q = p + ks * 32 + quad * 8;
                bf16x8 f;
#pragma unroll
                for (int jj = 0; jj < 8; ++jj) f[jj] = (bf16_t)q[jj];
                wof[ks] = f;
            }
            float bo = VEC[FV_BOUT + o];
#pragma unroll
            for (int mt = 0; mt < 2; ++mt) {
                bf16x8 af[4];
#pragma unroll
                for (int ks = 0; ks < 4; ++ks)
                    af[ks] = *(const bf16x8*)(HA + (mt * 16 + ln) * HAS + ks * 32 + quad * 8);
                f32x4 c = {0.f, 0.f, 0.f, 0.f};
#pragma unroll
                for (int ks = 0; ks < 4; ++ks) c = MFMA(af[ks], wof[ks], c);
#pragma unroll
                for (int reg = 0; reg < 4; ++reg)
                    out[((size_t)(b0 + mt) * Tt + t0 + quad * 4 + reg) * OUT_DIM + o] = c[reg] + bo;
            }
        }
        __syncthreads();
    }
}

// =====================================================================
extern "C" void kernel_launch(void* const* d_in, const int* in_sizes, int n_in,
                              void* d_out, int out_size, void* d_ws, size_t ws_size,
                              hipStream_t stream) {
    const float* x      = (const float*)d_in[0];
    const int*   is_init= (const int*)  d_in[1];
    const float* hx     = (const float*)d_in[2];
    const float* W1     = (const float*)d_in[3];
    const float* b1     = (const float*)d_in[4];
    const float* g1     = (const float*)d_in[5];
    const float* be1    = (const float*)d_in[6];
    const float* W2     = (const float*)d_in[7];
    const float* b2     = (const float*)d_in[8];
    const float* g2     = (const float*)d_in[9];
    const float* be2    = (const float*)d_in[10];
    const float* Wih    = (const float*)d_in[11];
    const float* Whh    = (const float*)d_in[12];
    const float* bih    = (const float*)d_in[13];
    const float* bhh    = (const float*)d_in[14];
    const float* Wout   = (const float*)d_in[15];
    const float* bout   = (const float*)d_in[16];
    float* out = (float*)d_out;

    if (d_ws != nullptr && ws_size >= (size_t)WS_NEED) {
        bf16_t* wsb = (bf16_t*)d_ws;
        float*  E   = (float*)((char*)d_ws + WS_E_OFF);
        int*    R   = (int*)  ((char*)d_ws + WS_R_OFF);
        int*    RA  = (int*)  ((char*)d_ws + WS_RA_OFF);

        cvt_weights<<<WS_ELEMS / 256, 256, 0, stream>>>(W1, W2, Wih, Whh, Wout, wsb, RA);

        hipFuncSetAttribute((const void*)gru_pass1,
                            hipFuncAttributeMaxDynamicSharedMemorySize, P1_SMEM);
        gru_pass1<<<dim3(Bb / BPB1, NTILE), 256, P1_SMEM, stream>>>(
            x, is_init, hx, b1, g1, be1, b2, g2, be2, bih, bhh, bout,
            wsb, E, R, out);

        gru_fixp<<<dim3(Bb / 16, NTILE - 1), 256, 0, stream>>>(
            x, is_init, b1, g1, be1, b2, g2, be2, bih, bhh, bout,
            wsb, E, R, RA, out);

        gru_sweep<<<Bb, 128, 0, stream>>>(
            x, is_init, W1, b1, g1, be1, W2, b2, g2, be2,
            Wih, Whh, bih, bhh, Wout, bout, E, R, RA, out);
    } else {
        hipFuncSetAttribute((const void*)gru_seq,
                            hipFuncAttributeMaxDynamicSharedMemorySize, FSMEM);
        gru_seq<<<Bb / 2, 256, FSMEM, stream>>>(
            x, is_init, hx, W1, b1, g1, be1, W2, b2, g2, be2,
            Wih, Whh, bih, bhh, Wout, bout, out);
    }
}